// Round 6
// baseline (106.745 us; speedup 1.0000x reference)
//
#include <hip/hip_runtime.h>
#include <math.h>

// Problem constants
#define SEQ    2048
#define ROT    32
#define ROWS_PER_BLOCK 128
#define NTILES (131072 / ROWS_PER_BLOCK)   // 1024 blocks

#define AS1 __attribute__((address_space(1)))
#define AS3 __attribute__((address_space(3)))

// ---------------------------------------------------------------------------
// Fused kernel v10: v9 minus barrier1.
//
// v9 post-mortem: pipelined scan + early X prefetch -> 104.9us (best).
// Remaining structural cost: barrier1 serialized chip-wide X streaming
// behind the cold R DMA (~1.5us of idle HBM at t=0, all 1024 blocks
// resident). v10 removes it:
//   - wave 0 issues ALL 16 R->LDS DMA regions itself, then does a
//     WAVE-LOCAL `s_waitcnt vmcnt(0)` + sched_barrier(0) (rule 18: pins
//     the scan's ds_reads behind the wait) before the pipelined scan.
//     Params (Cs/Ss/Pi/Pj) are written and read by wave 0 only ->
//     intra-wave lgkmcnt ordering, no barrier needed.
//   - ALL waves issue their kk=0,1 X prefetch at t~0, no barrier ahead.
//   - the single remaining __syncthreads() (barrier2) publishes Ws + SC
//     and auto-drains each wave's outstanding X loads.
// X streaming starts at t=0; waves 1-3 never wait on the R fetch.
//
// sqrt(1024)=32 folded into the sin/cos tables. d_ws unused.
// ---------------------------------------------------------------------------
__global__ __launch_bounds__(256) void rotary_fused_kernel(
    const float* __restrict__ x,
    const float* __restrict__ thetas,
    const float* __restrict__ theta_scale,
    const float* __restrict__ R,        // r_matrix, 64x64 row-major
    const float* __restrict__ inv_freq,
    const int*   __restrict__ pairs,    // 32 x 2
    float*       __restrict__ out)
{
    __shared__ float Ws[64 * 64];       // 16 KB: R staged, scanned in place
    __shared__ float SCc[8 * 32];       // 32*cos per (pos-group, d)
    __shared__ float SCs[8 * 32];       // 32*sin per (pos-group, d)
    __shared__ float Cs[ROT], Ss[ROT];
    __shared__ int   Pi[ROT], Pj[ROT];

    const int T    = blockIdx.x;
    const int t    = threadIdx.x;
    const int wave = t >> 6;
    const int lane = t & 63;

    // ---- wave 0 issues ALL R -> Ws staging (16 regions, linear dest) ----
    if (wave == 0) {
        #pragma unroll
        for (int i = 0; i < 16; ++i) {
            int row = i * 4 + (lane >> 4);
            const float* gp = R + row * 64 + (lane & 15) * 4;
            __builtin_amdgcn_global_load_lds((const AS1 unsigned int*)gp,
                                             (AS3 unsigned int*)&Ws[i * 256], 16, 0, 0);
        }
    }

    // ---- X kk=0,1 prefetch: issued at t~0 by ALL waves, no barrier ahead ----
    const int rp = t >> 3;              // 0..31
    const int cg = t & 7;               // 0..7
    const int r0 = rp * 4;              // 4 contiguous rows per thread
    const float* xr0 = x + (size_t)T * (ROWS_PER_BLOCK * 64) + r0 * 64;
    float4 nx[2][4];
    #pragma unroll
    for (int m = 0; m < 4; ++m) nx[0][m] = *(const float4*)(xr0 + m * 64);
    #pragma unroll
    for (int m = 0; m < 4; ++m) nx[1][m] = *(const float4*)(xr0 + m * 64 + 4);

    // ---- rotation params: wave-0-local (written t<32, read by scan t<64) ----
    if (t < ROT) {
        float th = thetas[t] * theta_scale[0];
        float sv, cv;
        sincosf(th, &sv, &cv);
        Cs[t] = cv; Ss[t] = sv;
        Pi[t] = pairs[2 * t]; Pj[t] = pairs[2 * t + 1];
    }

    // ---- pos sincos tables, pre-scaled by sqrt(1024)=32 (read post-barrier) ----
    {
        int pg = t >> 5, d = t & 31;         // 8 pos-groups x 32 freqs = 256
        int pos = (T * 8 + pg) & (SEQ - 1);  // position = global_row/16 mod SEQ
        float sv, cv;
        sincosf((float)pos * inv_freq[d], &sv, &cv);
        SCc[t] = 32.0f * cv;
        SCs[t] = 32.0f * sv;
    }

    // ---- software-pipelined reverse Givens scan: Ws = T_0(T_1(...(T_31 R)))
    // Wave 0, thread t owns column t. Wave-LOCAL vmcnt(0) drains the R DMA
    // (and wave 0's own X prefetch); sched_barrier(0) pins the scan's
    // ds_reads behind it (rule 18). Waves 1-3 skip straight to barrier2.
    if (wave == 0) {
        asm volatile("s_waitcnt vmcnt(0)" ::: "memory");
        __builtin_amdgcn_sched_barrier(0);
        int   i  = Pi[31], j  = Pj[31];
        float c  = Cs[31], s  = Ss[31];
        int   i2 = Pi[30], j2 = Pj[30];
        float c2 = Cs[30], s2 = Ss[30];
        int   i3 = Pi[29], j3 = Pj[29];
        float wi  = Ws[i  * 64 + t];
        float wj  = Ws[j  * 64 + t];
        float ri2 = Ws[i2 * 64 + t];    // speculative rows for step 30
        float rj2 = Ws[j2 * 64 + t];
        for (int k = 31; k >= 0; --k) {
            float ni, nj;
            if (i != j) {
                ni = fmaf(c, wi, -s * wj);
                nj = fmaf(s, wi,  c * wj);
                Ws[i * 64 + t] = ni;
                Ws[j * 64 + t] = nj;
            } else {
                ni = s * wi;            // ref: set(ni) overwritten by nj=xi*s
                nj = ni;                // forwarding alias (i2==j => i2==i)
                Ws[i * 64 + t] = ni;
            }
            if (k == 0) break;
            // forward step-(k-1) speculative reads over step-k writes
            wi = (i2 == i) ? ni : ((i2 == j) ? nj : ri2);
            wj = (j2 == i) ? ni : ((j2 == j) ? nj : rj2);
            // rotate pipeline state
            i = i2; j = j2; c = c2; s = s2;
            i2 = i3; j2 = j3;
            int km2 = (k >= 2) ? (k - 2) : 0;   // static-addr coeffs, 1 ahead
            int km3 = (k >= 3) ? (k - 3) : 0;   // indices, 2 ahead
            c2 = Cs[km2]; s2 = Ss[km2];
            i3 = Pi[km3]; j3 = Pj[km3];
            ri2 = Ws[i2 * 64 + t];      // issued after step-k writes:
            rj2 = Ws[j2 * 64 + t];      // stale only w.r.t. step k-1 -> fwd
        }
    }
    __syncthreads();                    // the ONLY barrier: Ws + SC published,
                                        // each wave's X prefetch drained

    float acc[4][8];
    #pragma unroll
    for (int m = 0; m < 4; ++m)
        #pragma unroll
        for (int jj = 0; jj < 8; ++jj) acc[m][jj] = 0.0f;

    // ---- main loop: 16 kk steps, fully unrolled, 2-deep X pipeline ----
    #pragma unroll
    for (int kk = 0; kk < 16; ++kk) {
        const int b = kk & 1;           // static under full unroll
        float4 xv[4];
        #pragma unroll
        for (int m = 0; m < 4; ++m) xv[m] = nx[b][m];
        if (kk < 14) {                  // refill the freed buffer (kk+2)
            #pragma unroll
            for (int m = 0; m < 4; ++m)
                nx[b][m] = *(const float4*)(xr0 + m * 64 + ((kk + 2) << 2));
        }
        float4 wv[8];
        #pragma unroll
        for (int r = 0; r < 4; ++r) {
            wv[2 * r]     = *(const float4*)&Ws[(4 * kk + r) * 64 + cg * 8];
            wv[2 * r + 1] = *(const float4*)&Ws[(4 * kk + r) * 64 + cg * 8 + 4];
        }
        #pragma unroll
        for (int m = 0; m < 4; ++m) {
            const float xa[4] = {xv[m].x, xv[m].y, xv[m].z, xv[m].w};
            #pragma unroll
            for (int r = 0; r < 4; ++r) {
                const float4 w0 = wv[2 * r], w1 = wv[2 * r + 1];
                const float xs = xa[r];
                acc[m][0] = fmaf(xs, w0.x, acc[m][0]);
                acc[m][1] = fmaf(xs, w0.y, acc[m][1]);
                acc[m][2] = fmaf(xs, w0.z, acc[m][2]);
                acc[m][3] = fmaf(xs, w0.w, acc[m][3]);
                acc[m][4] = fmaf(xs, w1.x, acc[m][4]);
                acc[m][5] = fmaf(xs, w1.y, acc[m][5]);
                acc[m][6] = fmaf(xs, w1.z, acc[m][6]);
                acc[m][7] = fmaf(xs, w1.w, acc[m][7]);
            }
        }
    }

    // ---- RoPE epilogue in registers; coalesced 16B stores ----
    // r0 = 4*rp: the 4 rows never cross a 16-row position-group boundary.
    const int scb = ((r0 >> 4) << 5) + cg * 4;
    const float4 cv = *(const float4*)&SCc[scb];   // pre-scaled by 32
    const float4 sv = *(const float4*)&SCs[scb];
    const float cs4[4] = {cv.x, cv.y, cv.z, cv.w};
    const float sn4[4] = {sv.x, sv.y, sv.z, sv.w};

    float* og = out + (size_t)T * (ROWS_PER_BLOCK * 64);
    #pragma unroll
    for (int m = 0; m < 4; ++m) {
        int row = r0 + m;
        float o1[4], o2[4];
        #pragma unroll
        for (int d = 0; d < 4; ++d) {
            float a = acc[m][2 * d];       // even col -> x1
            float b = acc[m][2 * d + 1];   // odd col  -> x2
            o1[d] = a * cs4[d] - b * sn4[d];
            o2[d] = a * sn4[d] + b * cs4[d];
        }
        *(float4*)&og[row * 64 + cg * 4]      = make_float4(o1[0], o1[1], o1[2], o1[3]);
        *(float4*)&og[row * 64 + 32 + cg * 4] = make_float4(o2[0], o2[1], o2[2], o2[3]);
    }
}

extern "C" void kernel_launch(void* const* d_in, const int* in_sizes, int n_in,
                              void* d_out, int out_size, void* d_ws, size_t ws_size,
                              hipStream_t stream) {
    const float* x           = (const float*)d_in[0];
    const float* thetas      = (const float*)d_in[1];
    const float* theta_scale = (const float*)d_in[2];
    const float* r_matrix    = (const float*)d_in[3];
    const float* inv_freq    = (const float*)d_in[4];
    const int*   pairs       = (const int*)d_in[5];
    float*       out         = (float*)d_out;
    (void)d_ws; (void)ws_size;

    rotary_fused_kernel<<<NTILES, 256, 0, stream>>>(
        x, thetas, theta_scale, r_matrix, inv_freq, pairs, out);
}

// Round 7
// 102.902 us; speedup vs baseline: 1.0373x; 1.0373x over previous
//
#include <hip/hip_runtime.h>
#include <math.h>

// Problem constants
#define SEQ    2048
#define ROT    32
#define ROWS_PER_BLOCK 128
#define NTILES (131072 / ROWS_PER_BLOCK)   // 1024 blocks

#define AS1 __attribute__((address_space(1)))
#define AS3 __attribute__((address_space(3)))

// ---------------------------------------------------------------------------
// Fused kernel v11 == v9 (best measured: 104.92us). v10's barrier1 removal
// regressed +1.8us: the wave-local vmcnt(0) made wave 0's scan wait on its
// OWN X prefetch (vmcnt counts all the wave's VMEM), and single-wave R-DMA
// issue serialized; meanwhile barrier1 was never actually blocking HBM --
// waves 1-3's X prefetches saturate it during the R window anyway. Reverted.
//
// Structure (v9): single launch, all-global X, ~18.5 KB LDS.
//  (1) Software-pipelined reverse Givens scan (W = T_0..T_31 R applied to
//      R's rows in reverse): next step's row reads issued BEFORE current
//      step's writes, collisions forwarded in registers via cndmask;
//      indices/coeffs fetched 2 steps ahead. ~80 cyc/step critical path.
//  (2) kk=0,1 X loads issued right after barrier1 (vmcnt traffic) so ~8 MB
//      chip-wide HBM is in flight DURING the scan (ds ops wait only on
//      lgkmcnt); k-loop fully unrolled with static 2-deep nx rotation.
//
// sqrt(1024)=32 folded into the sin/cos tables. d_ws unused.
// ---------------------------------------------------------------------------
__global__ __launch_bounds__(256) void rotary_fused_kernel(
    const float* __restrict__ x,
    const float* __restrict__ thetas,
    const float* __restrict__ theta_scale,
    const float* __restrict__ R,        // r_matrix, 64x64 row-major
    const float* __restrict__ inv_freq,
    const int*   __restrict__ pairs,    // 32 x 2
    float*       __restrict__ out)
{
    __shared__ float Ws[64 * 64];       // 16 KB: R staged, scanned in place
    __shared__ float SCc[8 * 32];       // 32*cos per (pos-group, d)
    __shared__ float SCs[8 * 32];       // 32*sin per (pos-group, d)
    __shared__ float Cs[ROT], Ss[ROT];
    __shared__ int   Pi[ROT], Pj[ROT];

    const int T    = blockIdx.x;
    const int t    = threadIdx.x;
    const int wave = t >> 6;
    const int lane = t & 63;

    // ---- issue async R -> Ws staging (linear dest, 16B/lane) ----
    #pragma unroll
    for (int i = 0; i < 4; ++i) {
        int ri  = i * 4 + wave;              // region 0..15 -> rows 4ri..4ri+3
        int row = ri * 4 + (lane >> 4);
        const float* gp = R + row * 64 + (lane & 15) * 4;
        __builtin_amdgcn_global_load_lds((const AS1 unsigned int*)gp,
                                         (AS3 unsigned int*)&Ws[ri * 256], 16, 0, 0);
    }

    // ---- rotation params (scan inputs: must be pre-barrier1) ----
    if (t < ROT) {
        float th = thetas[t] * theta_scale[0];
        float sv, cv;
        sincosf(th, &sv, &cv);
        Cs[t] = cv; Ss[t] = sv;
        Pi[t] = pairs[2 * t]; Pj[t] = pairs[2 * t + 1];
    }

    // ---- pos sincos tables, pre-scaled by sqrt(1024)=32 (VALU, overlaps) ----
    {
        int pg = t >> 5, d = t & 31;         // 8 pos-groups x 32 freqs = 256
        int pos = (T * 8 + pg) & (SEQ - 1);  // position = global_row/16 mod SEQ
        float sv, cv;
        sincosf((float)pos * inv_freq[d], &sv, &cv);
        SCc[t] = 32.0f * cv;
        SCs[t] = 32.0f * sv;
    }
    __syncthreads();                    // barrier1: R staged + params visible

    // ---- X kk=0,1 loads issued NOW: in flight during the scan ----
    const int rp = t >> 3;              // 0..31
    const int cg = t & 7;               // 0..7
    const int r0 = rp * 4;              // 4 contiguous rows per thread
    const float* xr0 = x + (size_t)T * (ROWS_PER_BLOCK * 64) + r0 * 64;
    float4 nx[2][4];
    #pragma unroll
    for (int m = 0; m < 4; ++m) nx[0][m] = *(const float4*)(xr0 + m * 64);
    #pragma unroll
    for (int m = 0; m < 4; ++m) nx[1][m] = *(const float4*)(xr0 + m * 64 + 4);

    // ---- software-pipelined reverse Givens scan: Ws = T_0(T_1(...(T_31 R)))
    // Wave 0, thread t owns column t. Speculative next-step row reads are
    // issued before current-step writes; collisions forwarded in registers.
    if (t < 64) {
        int   i  = Pi[31], j  = Pj[31];
        float c  = Cs[31], s  = Ss[31];
        int   i2 = Pi[30], j2 = Pj[30];
        float c2 = Cs[30], s2 = Ss[30];
        int   i3 = Pi[29], j3 = Pj[29];
        float wi  = Ws[i  * 64 + t];
        float wj  = Ws[j  * 64 + t];
        float ri2 = Ws[i2 * 64 + t];    // speculative rows for step 30
        float rj2 = Ws[j2 * 64 + t];
        for (int k = 31; k >= 0; --k) {
            float ni, nj;
            if (i != j) {
                ni = fmaf(c, wi, -s * wj);
                nj = fmaf(s, wi,  c * wj);
                Ws[i * 64 + t] = ni;
                Ws[j * 64 + t] = nj;
            } else {
                ni = s * wi;            // ref: set(ni) overwritten by nj=xi*s
                nj = ni;                // forwarding alias (i2==j => i2==i)
                Ws[i * 64 + t] = ni;
            }
            if (k == 0) break;
            // forward step-(k-1) speculative reads over step-k writes
            wi = (i2 == i) ? ni : ((i2 == j) ? nj : ri2);
            wj = (j2 == i) ? ni : ((j2 == j) ? nj : rj2);
            // rotate pipeline state
            i = i2; j = j2; c = c2; s = s2;
            i2 = i3; j2 = j3;
            int km2 = (k >= 2) ? (k - 2) : 0;   // static-addr coeffs, 1 ahead
            int km3 = (k >= 3) ? (k - 3) : 0;   // indices, 2 ahead
            c2 = Cs[km2]; s2 = Ss[km2];
            i3 = Pi[km3]; j3 = Pj[km3];
            ri2 = Ws[i2 * 64 + t];      // issued after step-k writes:
            rj2 = Ws[j2 * 64 + t];      // stale only w.r.t. step k-1 -> fwd
        }
    }
    __syncthreads();                    // barrier2: scan complete (X in VGPRs)

    float acc[4][8];
    #pragma unroll
    for (int m = 0; m < 4; ++m)
        #pragma unroll
        for (int jj = 0; jj < 8; ++jj) acc[m][jj] = 0.0f;

    // ---- main loop: 16 kk steps, fully unrolled, 2-deep X pipeline ----
    #pragma unroll
    for (int kk = 0; kk < 16; ++kk) {
        const int b = kk & 1;           // static under full unroll
        float4 xv[4];
        #pragma unroll
        for (int m = 0; m < 4; ++m) xv[m] = nx[b][m];
        if (kk < 14) {                  // refill the freed buffer (kk+2)
            #pragma unroll
            for (int m = 0; m < 4; ++m)
                nx[b][m] = *(const float4*)(xr0 + m * 64 + ((kk + 2) << 2));
        }
        float4 wv[8];
        #pragma unroll
        for (int r = 0; r < 4; ++r) {
            wv[2 * r]     = *(const float4*)&Ws[(4 * kk + r) * 64 + cg * 8];
            wv[2 * r + 1] = *(const float4*)&Ws[(4 * kk + r) * 64 + cg * 8 + 4];
        }
        #pragma unroll
        for (int m = 0; m < 4; ++m) {
            const float xa[4] = {xv[m].x, xv[m].y, xv[m].z, xv[m].w};
            #pragma unroll
            for (int r = 0; r < 4; ++r) {
                const float4 w0 = wv[2 * r], w1 = wv[2 * r + 1];
                const float xs = xa[r];
                acc[m][0] = fmaf(xs, w0.x, acc[m][0]);
                acc[m][1] = fmaf(xs, w0.y, acc[m][1]);
                acc[m][2] = fmaf(xs, w0.z, acc[m][2]);
                acc[m][3] = fmaf(xs, w0.w, acc[m][3]);
                acc[m][4] = fmaf(xs, w1.x, acc[m][4]);
                acc[m][5] = fmaf(xs, w1.y, acc[m][5]);
                acc[m][6] = fmaf(xs, w1.z, acc[m][6]);
                acc[m][7] = fmaf(xs, w1.w, acc[m][7]);
            }
        }
    }

    // ---- RoPE epilogue in registers; coalesced 16B stores ----
    // r0 = 4*rp: the 4 rows never cross a 16-row position-group boundary.
    const int scb = ((r0 >> 4) << 5) + cg * 4;
    const float4 cv = *(const float4*)&SCc[scb];   // pre-scaled by 32
    const float4 sv = *(const float4*)&SCs[scb];
    const float cs4[4] = {cv.x, cv.y, cv.z, cv.w};
    const float sn4[4] = {sv.x, sv.y, sv.z, sv.w};

    float* og = out + (size_t)T * (ROWS_PER_BLOCK * 64);
    #pragma unroll
    for (int m = 0; m < 4; ++m) {
        int row = r0 + m;
        float o1[4], o2[4];
        #pragma unroll
        for (int d = 0; d < 4; ++d) {
            float a = acc[m][2 * d];       // even col -> x1
            float b = acc[m][2 * d + 1];   // odd col  -> x2
            o1[d] = a * cs4[d] - b * sn4[d];
            o2[d] = a * sn4[d] + b * cs4[d];
        }
        *(float4*)&og[row * 64 + cg * 4]      = make_float4(o1[0], o1[1], o1[2], o1[3]);
        *(float4*)&og[row * 64 + 32 + cg * 4] = make_float4(o2[0], o2[1], o2[2], o2[3]);
    }
}

extern "C" void kernel_launch(void* const* d_in, const int* in_sizes, int n_in,
                              void* d_out, int out_size, void* d_ws, size_t ws_size,
                              hipStream_t stream) {
    const float* x           = (const float*)d_in[0];
    const float* thetas      = (const float*)d_in[1];
    const float* theta_scale = (const float*)d_in[2];
    const float* r_matrix    = (const float*)d_in[3];
    const float* inv_freq    = (const float*)d_in[4];
    const int*   pairs       = (const int*)d_in[5];
    float*       out         = (float*)d_out;
    (void)d_ws; (void)ws_size;

    rotary_fused_kernel<<<NTILES, 256, 0, stream>>>(
        x, thetas, theta_scale, r_matrix, inv_freq, pairs, out);
}